// Round 7
// baseline (93.911 us; speedup 1.0000x reference)
//
#include <hip/hip_runtime.h>
#include <hip/hip_bf16.h>

#define BB 8
#define CC 128
#define NN 4096
#define KCQ 32

typedef unsigned short u16;
typedef unsigned int u32;
typedef unsigned char u8;
typedef __bf16 bf16x8 __attribute__((ext_vector_type(8)));
typedef float f32x4 __attribute__((ext_vector_type(4)));
typedef long i64;

typedef const __attribute__((address_space(1))) void gas_t;
typedef __attribute__((address_space(3))) void las_t;

__device__ __forceinline__ u16 f2bf(float f){
  u32 u = __builtin_bit_cast(u32, f);
  u32 r = u + 0x7FFFu + ((u >> 16) & 1u);
  return (u16)(r >> 16);
}
__device__ __forceinline__ u32 cvtpk(float lo, float hi){
  u32 r; asm("v_cvt_pk_bf16_f32 %0, %1, %2" : "=v"(r) : "v"(lo), "v"(hi)); return r;
}
__device__ __forceinline__ u32 pk_fp8x4(float a, float b, float c, float d){
  int v = 0;
  v = __builtin_amdgcn_cvt_pk_fp8_f32(a, b, v, false);
  v = __builtin_amdgcn_cvt_pk_fp8_f32(c, d, v, true);
  return (u32)v;
}
__device__ __forceinline__ void gload16(const void* g, void* l){
  __builtin_amdgcn_global_load_lds((gas_t*)g, (las_t*)l, 16, 0, 0);
}

// ---- kernel 0: weights f32 -> bf16 (Wq folds 1/sqrt(32)*log2(e) for exp2 softmax)
__global__ __launch_bounds__(256) void k_prep_w(const float* Wq, const float* Wk,
                                                const float* Wv, const float* Wo,
                                                u16* wsq, u16* wsk, u16* wsv, u16* wso){
  int i = blockIdx.x * 256 + threadIdx.x;
  const float SC = 0.2550350f; // log2(e)/sqrt(32)
  if (i < 4096)       wsq[i]        = f2bf(Wq[i] * SC);
  else if (i < 8192)  wsk[i-4096]   = f2bf(Wk[i-4096]);
  else if (i < 24576) wsv[i-8192]   = f2bf(Wv[i-8192]);
  else if (i < 40960) wso[i-24576]  = f2bf(Wo[i-24576]);
}

// ---- kernel 1: fused transpose+projection. 512 blocks x 256 thr; block = (b, 64-n tile).
// V is packed fp8 and routed via an LDS transpose so global stores are 64B-coalesced
// (direct per-lane dword stores were 4B tx at 16KB stride).
__global__ __launch_bounds__(256) void k_projx(const float* x, const u16* wq, const u16* wk,
                                               const u16* wv, u16* Qm, u16* Km, u8* Vt8){
  __shared__ __align__(16) u16 xL[64*132];   // 16896 B; vbuf overlays after xa loads
  int b = blockIdx.x >> 6, nb = (blockIdx.x & 63) * 64;
  int t = threadIdx.x;
  int n = t & 63, cg = t >> 6;
  #pragma unroll
  for (int it = 0; it < 32; ++it){
    int c = it*4 + cg;
    xL[n*132 + c] = f2bf(x[((size_t)b*CC + c)*NN + nb + n]);
  }
  __syncthreads();
  int w = t >> 6, l = t & 63, a = l & 15, g = l >> 4;
  int n0 = nb + w*16;
  bf16x8 xa[4];
  #pragma unroll
  for (int kc = 0; kc < 4; ++kc)
    xa[kc] = *(const bf16x8*)(xL + (w*16 + a)*132 + kc*32 + g*8);
  __syncthreads();                     // xL dead -> vbuf overlay safe

  // V first: pack fp8 into LDS [128 vchan][16 dwords], chunk-XOR by (row>>1)&3
  u32* vbuf = (u32*)xL;
  #pragma unroll
  for (int vt = 0; vt < 8; ++vt){
    f32x4 acc = {0.f,0.f,0.f,0.f};
    #pragma unroll
    for (int kc = 0; kc < 4; ++kc){
      bf16x8 wa = ((const bf16x8*)(wv + (size_t)(vt*16 + a) * CC))[kc*4 + g];
      acc = __builtin_amdgcn_mfma_f32_16x16x32_bf16(xa[kc], wa, acc, 0,0,0);
    }
    int row = vt*16 + a;
    vbuf[row*16 + ((w ^ ((row>>1)&3)) << 2) + g] = pk_fp8x4(acc[0], acc[1], acc[2], acc[3]);
  }

  #pragma unroll
  for (int qt = 0; qt < 2; ++qt){
    f32x4 accq = {0.f,0.f,0.f,0.f}, acck = {0.f,0.f,0.f,0.f};
    #pragma unroll
    for (int kc = 0; kc < 4; ++kc){
      bf16x8 wbq = ((const bf16x8*)(wq + (size_t)(qt*16 + a) * CC))[kc*4 + g];
      bf16x8 wbk = ((const bf16x8*)(wk + (size_t)(qt*16 + a) * CC))[kc*4 + g];
      accq = __builtin_amdgcn_mfma_f32_16x16x32_bf16(xa[kc], wbq, accq, 0,0,0);
      acck = __builtin_amdgcn_mfma_f32_16x16x32_bf16(xa[kc], wbk, acck, 0,0,0);
    }
    #pragma unroll
    for (int r = 0; r < 4; ++r){
      Qm[((size_t)b*NN + n0 + 4*g + r) * KCQ + qt*16 + a] = f2bf(accq[r]);
      Km[((size_t)b*NN + n0 + 4*g + r) * KCQ + qt*16 + a] = f2bf(acck[r]);
    }
  }
  __syncthreads();
  // coalesced V writeout: thread -> (row = t>>1, half = t&1), 2 x 16B, 64B tx per row
  {
    int row = t >> 1, hf = t & 1, key = (row >> 1) & 3;
    uint4 d0 = ((const uint4*)vbuf)[row*4 + ((hf*2    ) ^ key)];
    uint4 d1 = ((const uint4*)vbuf)[row*4 + ((hf*2 + 1) ^ key)];
    u8* dst = Vt8 + ((size_t)b*CC + row)*NN + nb + hf*32;
    *(uint4*)dst = d0;
    *(uint4*)(dst + 16) = d1;
  }
}

// ---- kernel 2: flash attention; m=0, fp8 PV, K in REGISTERS (self-staged per wave),
// single barrier + single vmcnt(3) per kt. Per phase t: stage V(t+1) (async LDS),
// prefetch K(t+1) to regs, QK(t), PV(t-1) [prev P from LDS], softmax(t) -> P[t&1].
// V triple-buffered (WAR per-wave only), P double-buffered (cross-wave behind barrier).
// LDS = 48K V + 16K P = 64K exactly -> 2 blocks/CU.
__global__ __launch_bounds__(512, 4) void k_attn(const u16* Qm, const u16* Km,
                                                 const u8* Vt8, u16* Ow){
  __shared__ __align__(16) char smem[65536];
  // V slot s(0..2): s*16384 + h*8192 + vchan*64  [128][64B] fp8, chunk-XOR ((row>>1)&3)
  // P slot p(0..1): 49152 + p*8192 + h*4096 + q*64 [64][64B] fp8, same swizzle
  // epilogue overlays: Cx [64][132] f32 at 0 (V slots 0-1); Ml [8][64] f32 at 36864 (slot 2)
  int bid = blockIdx.x;
  int b = bid & 7, qb = bid >> 3;    // one batch per XCD
  int t0 = threadIdx.x;
  int l = t0 & 63, a = l & 15, g = l >> 4;
  int w = t0 >> 6, h = w >> 2, wq = w & 3;
  int q0 = qb * 64;
  int kb0 = h * 2048;

  const u8* Vb = Vt8 + (size_t)b * CC * NN;

  // Q frags (all 64 queries) + K row pointer (self slice, coalesced 16B/lane)
  bf16x8 qf[4];
  #pragma unroll
  for (int qs = 0; qs < 4; ++qs)
    qf[qs] = ((const bf16x8*)(Qm + ((size_t)b*NN + q0 + qs*16 + a) * KCQ))[g];
  const u16* kPtr = Km + ((size_t)b*NN + kb0 + wq*16 + a) * KCQ + g*8;  // +2048 per tile

  f32x4 o[8];                        // [qs*2+st] = O^T[wq*32+st*16+4g+r][qs*16+a]
  #pragma unroll
  for (int i = 0; i < 8; ++i) o[i] = (f32x4){0.f,0.f,0.f,0.f};
  float ls[4] = {0.f, 0.f, 0.f, 0.f};

  // V staging: lane owns row wq*32+(l>>2), chunk l&3; source pre-swizzled by (row>>1)&3
  int schk = (l&3) ^ ((l>>3)&3);
  const u8* vSrc = Vb + (size_t)(wq*32 + (l>>2))*NN + kb0 + (schk << 4);
  int vOff = h*8192 + wq*2048 + l*16;
  auto stageV = [&](int t1, int sl){
    const u8* vs = vSrc + t1*64;
    char* vd = smem + sl*16384 + vOff;
    gload16(vs, vd);
    gload16(vs + (size_t)16*NN, vd + 1024);
  };

  const int cswz = (a >> 1) & 3;
  auto PV = [&](int ps, int vsl){
    const char* Vs = smem + vsl*16384 + h*8192;
    const char* Pr = smem + 49152 + ps*8192 + h*4096;
    __builtin_amdgcn_s_setprio(1);
    #pragma unroll
    for (int kk = 0; kk < 2; ++kk){
      int kx = (((kk*2 + (g>>1)) ^ cswz) << 4) + (g&1)*8;
      i64 vf0 = *(const i64*)(Vs + (wq*32 + a)*64 + kx);
      i64 vf1 = *(const i64*)(Vs + (wq*32 + 16 + a)*64 + kx);
      i64 pf[4];
      #pragma unroll
      for (int qs = 0; qs < 4; ++qs)
        pf[qs] = *(const i64*)(Pr + (qs*16 + a)*64 + kx);
      #pragma unroll
      for (int qs = 0; qs < 4; ++qs){
        o[qs*2  ] = __builtin_amdgcn_mfma_f32_16x16x32_fp8_fp8(vf0, pf[qs], o[qs*2  ], 0,0,0);
        o[qs*2+1] = __builtin_amdgcn_mfma_f32_16x16x32_fp8_fp8(vf1, pf[qs], o[qs*2+1], 0,0,0);
      }
    }
    __builtin_amdgcn_s_setprio(0);
  };

  // prologue: V(0) async; K(0) to regs (compiler-managed wait)
  stageV(0, 0);
  bf16x8 kfC = *(const bf16x8*)(kPtr);

  int vS = 1, vR = 2;                // vS = (t+1)%3 stage slot, vR = (t-1)%3 read slot
  for (int t = 0; t < 32; ++t){
    bf16x8 kfN;
    if (t < 31){
      kfN = *(const bf16x8*)(kPtr + (size_t)(t+1)*2048);
      stageV(t+1, vS);
    }
    // QK(t): S^T[key wq*16+4g+r][q qs*16+a]
    f32x4 sv[4];
    #pragma unroll
    for (int qs = 0; qs < 4; ++qs){
      f32x4 z = {0.f,0.f,0.f,0.f};
      sv[qs] = __builtin_amdgcn_mfma_f32_16x16x32_bf16(kfC, qf[qs], z, 0,0,0);
    }
    // PV(t-1): MFMA co-issues with softmax VALU below
    if (t > 0) PV((t&1)^1, vR);
    // softmax (m=0): p = exp2(s); fp8 pack into P[t&1]
    char* Pw = smem + 49152 + (t&1)*8192 + h*4096;
    #pragma unroll
    for (int qs = 0; qs < 4; ++qs){
      float p0 = __builtin_amdgcn_exp2f(sv[qs][0]);
      float p1 = __builtin_amdgcn_exp2f(sv[qs][1]);
      float p2 = __builtin_amdgcn_exp2f(sv[qs][2]);
      float p3 = __builtin_amdgcn_exp2f(sv[qs][3]);
      ls[qs] += (p0 + p1) + (p2 + p3);
      *(u32*)(Pw + (qs*16 + a)*64 + ((wq ^ cswz) << 4) + 4*g) = pk_fp8x4(p0, p1, p2, p3);
    }
    // single wait+barrier: V(t) landed (3 youngest = t+1's loads), P(t) visible
    if (t < 31) { asm volatile("s_waitcnt vmcnt(3) lgkmcnt(0)" ::: "memory"); }
    else        { asm volatile("s_waitcnt vmcnt(0) lgkmcnt(0)" ::: "memory"); }
    __builtin_amdgcn_s_barrier();
    kfC = kfN;
    vR = (vR == 2) ? 0 : vR + 1;
    vS = (vS == 2) ? 0 : vS + 1;
  }
  PV(1, vR);                         // tail: PV(31), P slot 1, V slot 1

  // epilogue: l reduce + publish; combine halves; write O bf16
  #pragma unroll
  for (int qs = 0; qs < 4; ++qs){
    ls[qs] += __shfl_xor(ls[qs], 16);
    ls[qs] += __shfl_xor(ls[qs], 32);
  }
  float* Ml = (float*)(smem + 36864);   // V slot 2 region (dead)
  if (l < 16){
    #pragma unroll
    for (int qs = 0; qs < 4; ++qs) Ml[w*64 + qs*16 + l] = ls[qs];
  }
  float* Cx = (float*)smem;             // V slots 0-1 (dead after next barrier)
  __syncthreads();
  if (h == 1){
    #pragma unroll
    for (int i = 0; i < 8; ++i){
      int qs = i >> 1, st = i & 1;
      *(f32x4*)(Cx + (qs*16 + a)*132 + wq*32 + st*16 + 4*g) = o[i];
    }
  }
  __syncthreads();
  if (h == 0){
    #pragma unroll
    for (int qs = 0; qs < 4; ++qs){
      float lsum = 0.f;
      #pragma unroll
      for (int ww = 0; ww < 8; ++ww) lsum += Ml[ww*64 + qs*16 + a];
      float inv = 1.f / lsum;
      #pragma unroll
      for (int st = 0; st < 2; ++st){
        f32x4 oc = o[qs*2 + st];
        const float* cx = Cx + (qs*16 + a)*132 + wq*32 + st*16 + 4*g;
        float v0 = (oc[0] + cx[0]) * inv;
        float v1 = (oc[1] + cx[1]) * inv;
        float v2 = (oc[2] + cx[2]) * inv;
        float v3 = (oc[3] + cx[3]) * inv;
        uint2 pk; pk.x = cvtpk(v0, v1); pk.y = cvtpk(v2, v3);
        *(uint2*)(Ow + ((size_t)b*NN + q0 + qs*16 + a)*CC + wq*32 + st*16 + 4*g) = pk;
      }
    }
  }
}

// ---- kernel 3: y = x + gamma * (O @ Wo^T), 1 wave/block, 16 n per wave
__global__ __launch_bounds__(64) void k_out(const u16* Ow, const u16* wo, const float* x,
                                            const float* gamma, float* out){
  int bid = blockIdx.x;
  int b = bid >> 8, nt = bid & 255;
  int nb = nt * 16;
  int l = threadIdx.x, a = l & 15, g = l >> 4;
  float gm = gamma[0];
  bf16x8 ob[4];
  #pragma unroll
  for (int kc = 0; kc < 4; ++kc)
    ob[kc] = ((const bf16x8*)(Ow + ((size_t)b*NN + nb + a) * CC))[kc*4 + g];
  #pragma unroll
  for (int ot = 0; ot < 8; ++ot){
    f32x4 acc = {0.f,0.f,0.f,0.f};
    #pragma unroll
    for (int kc = 0; kc < 4; ++kc){
      bf16x8 wf = ((const bf16x8*)(wo + (size_t)(ot*16 + a) * CC))[kc*4 + g];
      acc = __builtin_amdgcn_mfma_f32_16x16x32_bf16(wf, ob[kc], acc, 0,0,0);
    }
    #pragma unroll
    for (int r = 0; r < 4; ++r){
      size_t idx = ((size_t)b*CC + ot*16 + 4*g + r) * NN + nb + a;
      out[idx] = x[idx] + gm * acc[r];
    }
  }
}

extern "C" void kernel_launch(void* const* d_in, const int* in_sizes, int n_in,
                              void* d_out, int out_size, void* d_ws, size_t ws_size,
                              hipStream_t stream) {
  const float* x     = (const float*)d_in[0];
  const float* Wq    = (const float*)d_in[1];
  const float* Wk    = (const float*)d_in[2];
  const float* Wv    = (const float*)d_in[3];
  const float* Wo    = (const float*)d_in[4];
  const float* gamma = (const float*)d_in[5];
  float* out = (float*)d_out;

  u16* wsq = (u16*)d_ws;
  u16* wsk = wsq + 4096;
  u16* wsv = wsk + 4096;
  u16* wso = wsv + 16384;
  u16* Qm  = wso + 16384;
  u16* Km  = Qm + (size_t)BB*NN*KCQ;
  u8*  Vt8 = (u8*)(Km + (size_t)BB*NN*KCQ);
  u16* Ow  = (u16*)(Vt8 + (size_t)BB*CC*NN);

  hipLaunchKernelGGL(k_prep_w, dim3(160), dim3(256), 0, stream, Wq, Wk, Wv, Wo, wsq, wsk, wsv, wso);
  hipLaunchKernelGGL(k_projx,  dim3(512), dim3(256), 0, stream, x, wsq, wsk, wsv, Qm, Km, Vt8);
  hipLaunchKernelGGL(k_attn,   dim3(512), dim3(512), 0, stream, Qm, Km, Vt8, Ow);
  hipLaunchKernelGGL(k_out,    dim3(2048), dim3(64), 0, stream, Ow, wso, x, gamma, out);
}

// Round 8
// 73.028 us; speedup vs baseline: 1.2860x; 1.2860x over previous
//
#include <hip/hip_runtime.h>
#include <hip/hip_bf16.h>

#define BB 8
#define CC 128
#define NN 4096
#define KCQ 32

typedef unsigned short u16;
typedef unsigned int u32;
typedef unsigned char u8;
typedef __bf16 bf16x8 __attribute__((ext_vector_type(8)));
typedef float f32x4 __attribute__((ext_vector_type(4)));
typedef long i64;

typedef const __attribute__((address_space(1))) void gas_t;
typedef __attribute__((address_space(3))) void las_t;

__device__ __forceinline__ u16 f2bf(float f){
  u32 u = __builtin_bit_cast(u32, f);
  u32 r = u + 0x7FFFu + ((u >> 16) & 1u);
  return (u16)(r >> 16);
}
__device__ __forceinline__ u32 cvtpk(float lo, float hi){
  u32 r; asm("v_cvt_pk_bf16_f32 %0, %1, %2" : "=v"(r) : "v"(lo), "v"(hi)); return r;
}
__device__ __forceinline__ u32 pk_fp8x4(float a, float b, float c, float d){
  int v = 0;
  v = __builtin_amdgcn_cvt_pk_fp8_f32(a, b, v, false);
  v = __builtin_amdgcn_cvt_pk_fp8_f32(c, d, v, true);
  return (u32)v;
}
__device__ __forceinline__ void gload16(const void* g, void* l){
  __builtin_amdgcn_global_load_lds((gas_t*)g, (las_t*)l, 16, 0, 0);
}

// ---- kernel 0: weights f32 -> bf16 (Wq folds 1/sqrt(32)*log2(e) for exp2 softmax)
__global__ __launch_bounds__(256) void k_prep_w(const float* Wq, const float* Wk,
                                                const float* Wv, const float* Wo,
                                                u16* wsq, u16* wsk, u16* wsv, u16* wso){
  int i = blockIdx.x * 256 + threadIdx.x;
  const float SC = 0.2550350f; // log2(e)/sqrt(32)
  if (i < 4096)       wsq[i]        = f2bf(Wq[i] * SC);
  else if (i < 8192)  wsk[i-4096]   = f2bf(Wk[i-4096]);
  else if (i < 24576) wsv[i-8192]   = f2bf(Wv[i-8192]);
  else if (i < 40960) wso[i-24576]  = f2bf(Wo[i-24576]);
}

// ---- kernel 1: fused transpose+projection. 512 blocks x 512 thr (16 waves/CU).
// Per block: 64-n tile. Wave pair per n-slice ns = w>>1: even wave {Q0,Q1,K0,K1,V0,V1},
// odd wave {V2..V7} (24 MFMA each). V packed fp8 via LDS transpose, 64B-coalesced out.
__global__ __launch_bounds__(512) void k_projx(const float* x, const u16* wq, const u16* wk,
                                               const u16* wv, u16* Qm, u16* Km, u8* Vt8){
  __shared__ __align__(16) u16 xL[64*132];   // 16.9KB; vbuf (8KB) overlays after frag loads
  int b = blockIdx.x >> 6, nb = (blockIdx.x & 63) * 64;
  int t = threadIdx.x;
  int n = t & 63, cg = t >> 6;
  #pragma unroll
  for (int it = 0; it < 16; ++it){
    int c = it*8 + cg;
    xL[n*132 + c] = f2bf(x[((size_t)b*CC + c)*NN + nb + n]);
  }
  __syncthreads();
  int w = t >> 6, l = t & 63, a = l & 15, g = l >> 4;
  int ns = w >> 1, half = w & 1;
  int n0 = nb + ns*16;
  bf16x8 xa[4];
  #pragma unroll
  for (int kc = 0; kc < 4; ++kc)
    xa[kc] = *(const bf16x8*)(xL + (ns*16 + a)*132 + kc*32 + g*8);
  __syncthreads();                       // xL dead -> vbuf overlay safe

  u32* vbuf = (u32*)xL;                  // [128 vchan][16 dwords], chunk ^ ((row>>1)&3)
  auto Vjob = [&](int vt){
    f32x4 acc = {0.f,0.f,0.f,0.f};
    #pragma unroll
    for (int kc = 0; kc < 4; ++kc){
      bf16x8 wa = ((const bf16x8*)(wv + (size_t)(vt*16 + a) * CC))[kc*4 + g];
      acc = __builtin_amdgcn_mfma_f32_16x16x32_bf16(xa[kc], wa, acc, 0,0,0);
    }
    int row = vt*16 + a;                 // n-cols ns*16+4g+{0..3} -> chunk ns, dword g
    vbuf[row*16 + ((ns ^ ((a>>1)&3)) << 2) + g] = pk_fp8x4(acc[0], acc[1], acc[2], acc[3]);
  };

  if (half == 0){
    #pragma unroll
    for (int qt = 0; qt < 2; ++qt){
      f32x4 accq = {0.f,0.f,0.f,0.f}, acck = {0.f,0.f,0.f,0.f};
      #pragma unroll
      for (int kc = 0; kc < 4; ++kc){
        bf16x8 wbq = ((const bf16x8*)(wq + (size_t)(qt*16 + a) * CC))[kc*4 + g];
        bf16x8 wbk = ((const bf16x8*)(wk + (size_t)(qt*16 + a) * CC))[kc*4 + g];
        accq = __builtin_amdgcn_mfma_f32_16x16x32_bf16(xa[kc], wbq, accq, 0,0,0);
        acck = __builtin_amdgcn_mfma_f32_16x16x32_bf16(xa[kc], wbk, acck, 0,0,0);
      }
      #pragma unroll
      for (int r = 0; r < 4; ++r){
        Qm[((size_t)b*NN + n0 + 4*g + r) * KCQ + qt*16 + a] = f2bf(accq[r]);
        Km[((size_t)b*NN + n0 + 4*g + r) * KCQ + qt*16 + a] = f2bf(acck[r]);
      }
    }
    Vjob(0); Vjob(1);
  } else {
    #pragma unroll
    for (int vt = 2; vt < 8; ++vt) Vjob(vt);
  }
  __syncthreads();
  // coalesced V writeout: thread -> (row = t>>2, chunk = t&3): 16B each, 64B/row
  {
    int row = t >> 2, ck = t & 3, key = (row >> 1) & 3;
    uint4 d = ((const uint4*)vbuf)[row*4 + (ck ^ key)];
    *(uint4*)(Vt8 + ((size_t)b*CC + row)*NN + nb + ck*16) = d;
  }
}

// ---- kernel 2: flash attention + fused output projection/residual.
// Main loop unchanged from R7 (m=0, fp8 PV, K in regs, 1 barrier/kt, V 3-buf, P 2-buf).
// Epilogue: combine halves -> O[64q][128c] bf16 in LDS (swizzled, overlays dead P) ->
// all 8 waves GEMM vs Wo (16 MFMA each) -> out = x + gamma*(...), direct f32 write.
__global__ __launch_bounds__(512, 4) void k_attn(const u16* Qm, const u16* Km,
                                                 const u8* Vt8, const u16* wso,
                                                 const float* x, const float* gamma,
                                                 float* out){
  __shared__ __align__(16) char smem[65536];
  // V slot s(0..2): s*16384 + h*8192 + vchan*64  [128][64B] fp8, chunk-XOR ((row>>1)&3)
  // P slot p(0..1): 49152 + p*8192 + h*4096 + q*64 [64][64B] fp8, same swizzle
  // epilogue overlays: Cx [64][132] f32 @0; Ml [8][64] f32 @36864; Ol [64][128] bf16 @49152
  int bid = blockIdx.x;
  int b = bid & 7, qb = bid >> 3;    // one batch per XCD
  int t0 = threadIdx.x;
  int l = t0 & 63, a = l & 15, g = l >> 4;
  int w = t0 >> 6, h = w >> 2, wq = w & 3;
  int q0 = qb * 64;
  int kb0 = h * 2048;

  const u8* Vb = Vt8 + (size_t)b * CC * NN;

  bf16x8 qf[4];
  #pragma unroll
  for (int qs = 0; qs < 4; ++qs)
    qf[qs] = ((const bf16x8*)(Qm + ((size_t)b*NN + q0 + qs*16 + a) * KCQ))[g];
  const u16* kPtr = Km + ((size_t)b*NN + kb0 + wq*16 + a) * KCQ + g*8;

  f32x4 o[8];                        // [qs*2+st] = O^T[wq*32+st*16+4g+r][qs*16+a]
  #pragma unroll
  for (int i = 0; i < 8; ++i) o[i] = (f32x4){0.f,0.f,0.f,0.f};
  float ls[4] = {0.f, 0.f, 0.f, 0.f};

  int schk = (l&3) ^ ((l>>3)&3);
  const u8* vSrc = Vb + (size_t)(wq*32 + (l>>2))*NN + kb0 + (schk << 4);
  int vOff = h*8192 + wq*2048 + l*16;
  auto stageV = [&](int t1, int sl){
    const u8* vs = vSrc + t1*64;
    char* vd = smem + sl*16384 + vOff;
    gload16(vs, vd);
    gload16(vs + (size_t)16*NN, vd + 1024);
  };

  const int cswz = (a >> 1) & 3;
  auto PV = [&](int ps, int vsl){
    const char* Vs = smem + vsl*16384 + h*8192;
    const char* Pr = smem + 49152 + ps*8192 + h*4096;
    __builtin_amdgcn_s_setprio(1);
    #pragma unroll
    for (int kk = 0; kk < 2; ++kk){
      int kx = (((kk*2 + (g>>1)) ^ cswz) << 4) + (g&1)*8;
      i64 vf0 = *(const i64*)(Vs + (wq*32 + a)*64 + kx);
      i64 vf1 = *(const i64*)(Vs + (wq*32 + 16 + a)*64 + kx);
      i64 pf[4];
      #pragma unroll
      for (int qs = 0; qs < 4; ++qs)
        pf[qs] = *(const i64*)(Pr + (qs*16 + a)*64 + kx);
      #pragma unroll
      for (int qs = 0; qs < 4; ++qs){
        o[qs*2  ] = __builtin_amdgcn_mfma_f32_16x16x32_fp8_fp8(vf0, pf[qs], o[qs*2  ], 0,0,0);
        o[qs*2+1] = __builtin_amdgcn_mfma_f32_16x16x32_fp8_fp8(vf1, pf[qs], o[qs*2+1], 0,0,0);
      }
    }
    __builtin_amdgcn_s_setprio(0);
  };

  stageV(0, 0);
  bf16x8 kfC = *(const bf16x8*)(kPtr);

  int vS = 1, vR = 2;
  for (int t = 0; t < 32; ++t){
    bf16x8 kfN;
    if (t < 31){
      kfN = *(const bf16x8*)(kPtr + (size_t)(t+1)*2048);
      stageV(t+1, vS);
    }
    f32x4 sv[4];
    #pragma unroll
    for (int qs = 0; qs < 4; ++qs){
      f32x4 z = {0.f,0.f,0.f,0.f};
      sv[qs] = __builtin_amdgcn_mfma_f32_16x16x32_bf16(kfC, qf[qs], z, 0,0,0);
    }
    if (t > 0) PV((t&1)^1, vR);
    char* Pw = smem + 49152 + (t&1)*8192 + h*4096;
    #pragma unroll
    for (int qs = 0; qs < 4; ++qs){
      float p0 = __builtin_amdgcn_exp2f(sv[qs][0]);
      float p1 = __builtin_amdgcn_exp2f(sv[qs][1]);
      float p2 = __builtin_amdgcn_exp2f(sv[qs][2]);
      float p3 = __builtin_amdgcn_exp2f(sv[qs][3]);
      ls[qs] += (p0 + p1) + (p2 + p3);
      *(u32*)(Pw + (qs*16 + a)*64 + ((wq ^ cswz) << 4) + 4*g) = pk_fp8x4(p0, p1, p2, p3);
    }
    if (t < 31) { asm volatile("s_waitcnt vmcnt(3) lgkmcnt(0)" ::: "memory"); }
    else        { asm volatile("s_waitcnt vmcnt(0) lgkmcnt(0)" ::: "memory"); }
    __builtin_amdgcn_s_barrier();
    kfC = kfN;
    vR = (vR == 2) ? 0 : vR + 1;
    vS = (vS == 2) ? 0 : vS + 1;
  }
  PV(1, vR);                         // tail: PV(31)

  // ---- fused epilogue ----
  #pragma unroll
  for (int qs = 0; qs < 4; ++qs){
    ls[qs] += __shfl_xor(ls[qs], 16);
    ls[qs] += __shfl_xor(ls[qs], 32);
  }
  float* Ml = (float*)(smem + 36864);   // V slot 2 (dead after loop-exit barrier)
  if (l < 16){
    #pragma unroll
    for (int qs = 0; qs < 4; ++qs) Ml[w*64 + qs*16 + l] = ls[qs];
  }
  float* Cx = (float*)smem;             // V slots 0-1 (dead)
  __syncthreads();                      // X1
  if (h == 1){
    #pragma unroll
    for (int i = 0; i < 8; ++i){
      int qs = i >> 1, st = i & 1;
      *(f32x4*)(Cx + (qs*16 + a)*132 + wq*32 + st*16 + 4*g) = o[i];
    }
  }
  __syncthreads();                      // X2
  u16* Ol = (u16*)(smem + 49152);       // [64q][128c] bf16, chunk16B ^ (q&7)
  if (h == 0){
    #pragma unroll
    for (int qs = 0; qs < 4; ++qs){
      float lsum = 0.f;
      #pragma unroll
      for (int ww = 0; ww < 8; ++ww) lsum += Ml[ww*64 + qs*16 + a];
      float inv = 1.f / lsum;
      #pragma unroll
      for (int st = 0; st < 2; ++st){
        f32x4 oc = o[qs*2 + st];
        const float* cx = Cx + (qs*16 + a)*132 + wq*32 + st*16 + 4*g;
        uint2 pk;
        pk.x = cvtpk((oc[0] + cx[0]) * inv, (oc[1] + cx[1]) * inv);
        pk.y = cvtpk((oc[2] + cx[2]) * inv, (oc[3] + cx[3]) * inv);
        int chunk = (wq*4 + st*2 + (g>>1)) ^ (a & 7);   // c0 = wq*32+st*16+4g
        *(uint2*)((char*)Ol + (qs*16 + a)*256 + chunk*16 + (g&1)*8) = pk;
      }
    }
  }
  __syncthreads();                      // X3
  // out-GEMM: wave w -> out rows [w*16, w*16+16), all 64 q. out = x + gm * O@Wo^T
  float gm = gamma[0];
  f32x4 acc2[4];
  #pragma unroll
  for (int qs = 0; qs < 4; ++qs) acc2[qs] = (f32x4){0.f,0.f,0.f,0.f};
  #pragma unroll
  for (int kc = 0; kc < 4; ++kc){
    bf16x8 wof = *(const bf16x8*)(wso + (size_t)(w*16 + a)*CC + kc*32 + g*8);
    #pragma unroll
    for (int qs = 0; qs < 4; ++qs){
      int chunk = (kc*4 + g) ^ (a & 7);
      bf16x8 of = *(const bf16x8*)((const char*)Ol + (qs*16 + a)*256 + chunk*16);
      acc2[qs] = __builtin_amdgcn_mfma_f32_16x16x32_bf16(wof, of, acc2[qs], 0,0,0);
    }
  }
  #pragma unroll
  for (int qs = 0; qs < 4; ++qs){
    #pragma unroll
    for (int r = 0; r < 4; ++r){
      size_t idx = ((size_t)b*CC + w*16 + 4*g + r)*NN + q0 + qs*16 + a;
      out[idx] = x[idx] + gm * acc2[qs][r];
    }
  }
}

extern "C" void kernel_launch(void* const* d_in, const int* in_sizes, int n_in,
                              void* d_out, int out_size, void* d_ws, size_t ws_size,
                              hipStream_t stream) {
  const float* x     = (const float*)d_in[0];
  const float* Wq    = (const float*)d_in[1];
  const float* Wk    = (const float*)d_in[2];
  const float* Wv    = (const float*)d_in[3];
  const float* Wo    = (const float*)d_in[4];
  const float* gamma = (const float*)d_in[5];
  float* out = (float*)d_out;

  u16* wsq = (u16*)d_ws;
  u16* wsk = wsq + 4096;
  u16* wsv = wsk + 4096;
  u16* wso = wsv + 16384;
  u16* Qm  = wso + 16384;
  u16* Km  = Qm + (size_t)BB*NN*KCQ;
  u8*  Vt8 = (u8*)(Km + (size_t)BB*NN*KCQ);

  hipLaunchKernelGGL(k_prep_w, dim3(160), dim3(256), 0, stream, Wq, Wk, Wv, Wo, wsq, wsk, wsv, wso);
  hipLaunchKernelGGL(k_projx,  dim3(512), dim3(512), 0, stream, x, wsq, wsk, wsv, Qm, Km, Vt8);
  hipLaunchKernelGGL(k_attn,   dim3(512), dim3(512), 0, stream, Qm, Km, Vt8, wso, x, gamma, out);
}